// Round 9
// baseline (1445.666 us; speedup 1.0000x reference)
//
#include <hip/hip_runtime.h>

typedef unsigned short u16;
typedef unsigned int u32;

#define N_ATOMS 100000
#define N_BONDS 200000
#define N_EDGES 100000
#define HIDDEN 300
#define HP 320
#define ATOM_FDIM 133
#define BOND_FDIM 147
#define CATP 448
#define N_MOLS 2000

typedef __bf16 bf16x8 __attribute__((ext_vector_type(8)));
typedef float f32x4 __attribute__((ext_vector_type(4)));

__device__ __forceinline__ u16 f2bf(float f) {
    union { float f; u32 u; } x; x.f = f;
    u32 u = x.u;
    u32 r = u + 0x7fffu + ((u >> 16) & 1u);
    return (u16)(r >> 16);
}
__device__ __forceinline__ float bf2f(u16 h) {
    union { u32 u; float f; } x; x.u = ((u32)h) << 16;
    return x.f;
}

union U8 { uint4 v; u16 h[8]; };
union U4 { uint2 v; u16 h[4]; };

// ============ R1-structure linear-A MFMA GEMM (proven 2.5 TB/s) ============
// Block: 128 rows x 64 cols, 256 threads = 4 waves (2x2 wr/wc).
// blockIdx.x = N-block (fastest -> A-panel L2 reuse), blockIdx.y = M-block.
// Swapped-operand MFMA: acc = mfma(B,A) -> lane holds 4 consecutive C-cols.
//  ASRC 0: linear bf16 rows (stride lda), RELU flag applies relu on stage
//  ASRC 2: f32 rows (width lda), zero-pad to K
//  ASRC 3: cat [amsg3 (HP-stride, cols 0..303; 300+ are zeros) | f32 f_atoms]
// EP 1: O1 = bf16(acc);  EP 3: O1 = bf16(relu(acc + (col<Nout?bias:0)))
template<int ASRC, int EP, int KSTEPS, int RELU>
__global__ __launch_bounds__(256) void k_gemmL(
    const u16* __restrict__ A, const float* __restrict__ AF,
    int lda, int M, const u16* __restrict__ Bt, int ldb,
    int Nout, const float* __restrict__ bias, u16* __restrict__ O1)
{
    __shared__ __align__(16) u16 As[128 * 40];
    __shared__ __align__(16) u16 Bs[64 * 40];

    const int tid = threadIdx.x;
    const int n0 = blockIdx.x * 64;
    const int row0 = blockIdx.y * 128;
    const int lane = tid & 63;
    const int w = tid >> 6, wr = w >> 1, wc = w & 1;
    const int lrow = lane & 15;
    const int g = lane >> 4;
    const int lkb = g * 8;

    // staging map: A = 128 rows x 4 kgroups (2 chunks/thread), B = 64 x 4
    const int rA0 = tid >> 2, kg = tid & 3, kofs = kg * 8;
    const int rA1 = rA0 + 64;
    int r0 = row0 + rA0; if (r0 >= M) r0 = M - 1;
    int r1 = row0 + rA1; if (r1 >= M) r1 = M - 1;

    auto loadA = [&](int r, int k0) -> uint4 {
        U8 u;
        if constexpr (ASRC == 0) {
            u.v = *(const uint4*)(A + (size_t)r * lda + k0 + kofs);
            if constexpr (RELU) {
#pragma unroll
                for (int e = 0; e < 8; e++) u.h[e] = (u.h[e] & 0x8000u) ? (u16)0 : u.h[e];
            }
        } else if constexpr (ASRC == 2) {
            size_t fb = (size_t)r * lda;
#pragma unroll
            for (int e = 0; e < 8; e++) {
                int col = k0 + kofs + e;
                u.h[e] = (col < lda) ? f2bf(AF[fb + col]) : (u16)0;
            }
        } else {
            int col0 = k0 + kofs;
            if (col0 < 304) {
                u.v = *(const uint4*)(A + (size_t)r * HP + col0);
            } else {
                size_t fb = (size_t)r * ATOM_FDIM;
#pragma unroll
                for (int e = 0; e < 8; e++) {
                    int col = col0 + e - 304;
                    u.h[e] = (col < ATOM_FDIM) ? f2bf(AF[fb + col]) : (u16)0;
                }
            }
        }
        return u.v;
    };

    const u16* pb = Bt + (size_t)(n0 + rA0) * ldb + kofs;

    uint4 va0 = loadA(r0, 0);
    uint4 va1 = loadA(r1, 0);
    uint4 vb  = *(const uint4*)pb;

    f32x4 acc[4][2] = {};

    constexpr int K = KSTEPS * 32;
    for (int k0 = 0; k0 < K; k0 += 32) {
        *(uint4*)&As[rA0 * 40 + kofs] = va0;
        *(uint4*)&As[rA1 * 40 + kofs] = va1;
        *(uint4*)&Bs[rA0 * 40 + kofs] = vb;
        __syncthreads();
        if (k0 + 32 < K) {
            va0 = loadA(r0, k0 + 32);
            va1 = loadA(r1, k0 + 32);
            vb  = *(const uint4*)(pb + k0 + 32);
        }
        bf16x8 af[4], bfr[2];
#pragma unroll
        for (int m = 0; m < 4; m++)
            af[m] = *(const bf16x8*)&As[(wr * 64 + m * 16 + lrow) * 40 + lkb];
#pragma unroll
        for (int n = 0; n < 2; n++)
            bfr[n] = *(const bf16x8*)&Bs[(wc * 32 + n * 16 + lrow) * 40 + lkb];
#pragma unroll
        for (int m = 0; m < 4; m++)
#pragma unroll
            for (int n = 0; n < 2; n++)
                acc[m][n] = __builtin_amdgcn_mfma_f32_16x16x32_bf16(bfr[n], af[m], acc[m][n], 0, 0, 0);
        __syncthreads();
    }

    // swapped layout: C-row = row0+wr*64+m*16+lrow ; C-cols = n0+wc*32+n*16+g*4+q
#pragma unroll
    for (int m = 0; m < 4; m++) {
        const int row = row0 + wr * 64 + m * 16 + lrow;
        if (row >= M) continue;
#pragma unroll
        for (int n = 0; n < 2; n++) {
            const int colb = n0 + wc * 32 + n * 16 + g * 4;
            U4 o;
            if constexpr (EP == 1) {
#pragma unroll
                for (int q = 0; q < 4; q++) o.h[q] = f2bf(acc[m][n][q]);
            } else {
#pragma unroll
                for (int q = 0; q < 4; q++) {
                    float x = acc[m][n][q] + ((colb + q) < Nout ? bias[colb + q] : 0.f);
                    o.h[q] = f2bf(fmaxf(x, 0.f));
                }
            }
            *(uint2*)&O1[(size_t)row * HP + colb] = o.v;
        }
    }
}

// =================== barrier-free direct-from-global MFMA GEMM ===================
// (node head ASRC0 and edge head ASRC4/WAVEM1 — unchanged, measured fine)
template<int ASRC, int EP, int KSTEPS, int NFW, int WAVEM>
__global__ __launch_bounds__(256) void k_gemm(
    const float* __restrict__ fsrc, const u16* __restrict__ src16,
    const u16* __restrict__ src16b, const int* __restrict__ i1,
    const int* __restrict__ i2, int lda, int M,
    const u16* __restrict__ Bt, int ldb,
    int Nout, float* __restrict__ Cf, int ldc,
    const float* __restrict__ bias, u16* __restrict__ O1,
    const u16* __restrict__ inp_in)
{
    const int tid = threadIdx.x;
    const int lane = tid & 63;
    const int w = tid >> 6;
    const int lrow = lane & 15;
    const int lkb = (lane >> 4) * 8;

    int row0, ncol0;
    if constexpr (WAVEM) { row0 = blockIdx.x * 128 + w * 32; ncol0 = 0; }
    else                 { row0 = blockIdx.x * 32;           ncol0 = w * (NFW * 16); }

    const u16* pa[2] = {nullptr, nullptr};
    const u16* pa2[2] = {nullptr, nullptr};
#pragma unroll
    for (int m = 0; m < 2; m++) {
        int r = row0 + m * 16 + lrow; if (r >= M) r = M - 1;
        if constexpr (ASRC == 0) pa[m] = src16 + (size_t)r * lda + lkb;
        if constexpr (ASRC == 4) {
            int e = 2 * r;
            pa[m]  = src16 + (size_t)i1[e] * HP + lkb;
            pa2[m] = src16 + (size_t)i1[i2[e]] * HP + lkb;
        }
    }

    const u16* pb[NFW];
#pragma unroll
    for (int n = 0; n < NFW; n++)
        pb[n] = Bt + (size_t)(ncol0 + n * 16 + lrow) * ldb + lkb;

    auto loadAfrag = [&](int m, int k0) -> bf16x8 {
        U8 u;
        if constexpr (ASRC == 0) {
            u.v = *(const uint4*)(pa[m] + k0);
        } else {
            U8 x, y; x.v = *(const uint4*)(pa[m] + k0); y.v = *(const uint4*)(pa2[m] + k0);
#pragma unroll
            for (int e = 0; e < 8; e++)
                u.h[e] = f2bf(0.5f * (bf2f(x.h[e]) + bf2f(y.h[e])));
        }
        return *(bf16x8*)&u;
    };

    f32x4 acc[2][NFW] = {};

#pragma unroll
    for (int ks = 0; ks < KSTEPS; ks++) {
        const int k0 = ks * 32;
        bf16x8 a0 = loadAfrag(0, k0);
        bf16x8 a1 = loadAfrag(1, k0);
        bf16x8 bfr[NFW];
#pragma unroll
        for (int n = 0; n < NFW; n++) bfr[n] = *(const bf16x8*)(pb[n] + k0);
#pragma unroll
        for (int n = 0; n < NFW; n++) {
            acc[0][n] = __builtin_amdgcn_mfma_f32_16x16x32_bf16(a0, bfr[n], acc[0][n], 0, 0, 0);
            acc[1][n] = __builtin_amdgcn_mfma_f32_16x16x32_bf16(a1, bfr[n], acc[1][n], 0, 0, 0);
        }
    }

    const int orow = (lane >> 4) * 4;
    const int ocol = lane & 15;
#pragma unroll
    for (int m = 0; m < 2; m++) {
#pragma unroll
        for (int n = 0; n < NFW; n++) {
#pragma unroll
            for (int q = 0; q < 4; q++) {
                int grow = row0 + m * 16 + orow + q;
                int gcol = ncol0 + n * 16 + ocol;
                float v = acc[m][n][q];
                if constexpr (EP == 0) {
                    if (grow < M && gcol < Nout)
                        Cf[(size_t)grow * ldc + gcol] = v + bias[gcol];
                } else {
                    if (grow < M) O1[(size_t)grow * HP + gcol] = f2bf(v);
                }
            }
        }
    }
}

// ---------------- weight pack: Bt[n][k] = W[k][n], bf16, zero-padded ----------------
__global__ void k_pack_wt(const float* __restrict__ W, u16* __restrict__ Bt,
                          int K, int N, int Kp, int Np)
{
    int idx = blockIdx.x * 256 + threadIdx.x;
    if (idx >= Np * Kp) return;
    int n = idx / Kp, k = idx - n * Kp;
    Bt[idx] = (n < N && k < K) ? f2bf(W[(size_t)k * N + n]) : (u16)0;
}

// W_o pack with the [amsg(300) | pad4 | f_atoms(133) | pad] column reorder
__global__ void k_pack_wo(const float* __restrict__ W, u16* __restrict__ Bt)
{
    int idx = blockIdx.x * 256 + threadIdx.x;
    if (idx >= 320 * CATP) return;
    int n = idx / CATP, k = idx - n * CATP;
    float v = 0.f;
    if (n < HIDDEN) {
        if (k < HIDDEN) v = W[(size_t)(ATOM_FDIM + k) * HIDDEN + n];
        else if (k >= 304 && k < 304 + ATOM_FDIM) v = W[(size_t)(k - 304) * HIDDEN + n];
    }
    Bt[idx] = f2bf(v);
}

// ---------------- aP[a] = sum_j P[a2b[a][j]]   (plain sum, no relu) ----------------
__global__ __launch_bounds__(256) void k_aggregate(const u16* __restrict__ P,
    const int* __restrict__ a2b, u16* __restrict__ aP)
{
    int idx = blockIdx.x * 256 + threadIdx.x;
    if (idx >= N_ATOMS * 40) return;
    int a = idx / 40, c = (idx - a * 40) * 8;
    float s[8] = {};
#pragma unroll
    for (int j = 0; j < 6; j++) {
        int b = a2b[a * 6 + j];
        U8 u; u.v = *(const uint4*)&P[(size_t)b * HP + c];
#pragma unroll
        for (int i = 0; i < 8; i++) s[i] += bf2f(u.h[i]);
    }
    U8 o;
#pragma unroll
    for (int i = 0; i < 8; i++) o.h[i] = f2bf(s[i]);
    *(uint4*)&aP[(size_t)a * HP + c] = o.v;
}

// -------- rh'[b] = relu(inp[b] + aP[b2a[b]] - P[b^1])   (next msg, post-relu) --------
__global__ __launch_bounds__(256) void k_combine(const u16* __restrict__ inp,
    const u16* __restrict__ P, const u16* __restrict__ aP,
    const int* __restrict__ b2a, u16* __restrict__ rh)
{
    int idx = blockIdx.x * 256 + threadIdx.x;
    if (idx >= N_BONDS * 40) return;
    int b = idx / 40, c = (idx - b * 40) * 8;
    int a = b2a[b];
    U8 x; x.v = *(const uint4*)&inp[(size_t)b * HP + c];
    U8 y; y.v = *(const uint4*)&P[(size_t)(b ^ 1) * HP + c];
    U8 z; z.v = *(const uint4*)&aP[(size_t)a * HP + c];
    U8 o;
#pragma unroll
    for (int i = 0; i < 8; i++)
        o.h[i] = f2bf(fmaxf(bf2f(x.h[i]) + bf2f(z.h[i]) - bf2f(y.h[i]), 0.f));
    *(uint4*)&rh[(size_t)b * HP + c] = o.v;
}

// ---------------- per-molecule segment sum (graph_idx sorted) ----------------
__device__ __forceinline__ int lower_bound_i(const int* a, int n, int v) {
    int lo = 0, hi = n;
    while (lo < hi) { int mid = (lo + hi) >> 1; if (a[mid] < v) lo = mid + 1; else hi = mid; }
    return lo;
}
__global__ __launch_bounds__(320) void k_segsum(const u16* __restrict__ ah,
    const int* __restrict__ gidx, float* __restrict__ gemb)
{
    int g = blockIdx.x;
    int c = threadIdx.x;
    int s = lower_bound_i(gidx, N_ATOMS, g);
    int e = lower_bound_i(gidx, N_ATOMS, g + 1);
    float sum = 0.f;
    for (int a = s; a < e; a++) sum += bf2f(ah[(size_t)a * HP + c]);
    gemb[(size_t)g * HP + c] = sum;
}

// ---------------- graph head (fp32) ----------------
__global__ __launch_bounds__(320) void k_g1(const float* __restrict__ gemb,
    const float* __restrict__ W, const float* __restrict__ b, float* __restrict__ gh)
{
    int g = blockIdx.x, j = threadIdx.x;
    float acc = 0.f;
    if (j < HIDDEN) {
        acc = b[j];
        for (int k = 0; k < HIDDEN; k++)
            acc = fmaf(gemb[(size_t)g * HP + k], W[(size_t)k * HIDDEN + j], acc);
        acc = fmaxf(acc, 0.f);
    }
    gh[(size_t)g * HP + j] = (j < HIDDEN) ? acc : 0.f;
}
__global__ __launch_bounds__(64) void k_g2(const float* __restrict__ gh,
    const float* __restrict__ W, const float* __restrict__ b, float* __restrict__ out)
{
    int g = blockIdx.x, l = threadIdx.x;
    float acc = 0.f;
    for (int j = l; j < HIDDEN; j += 64) acc += gh[(size_t)g * HP + j] * W[j];
#pragma unroll
    for (int off = 32; off; off >>= 1) acc += __shfl_down(acc, off, 64);
    if (l == 0) out[g] = acc + b[0];
}

extern "C" void kernel_launch(void* const* d_in, const int* in_sizes, int n_in,
                              void* d_out, int out_size, void* d_ws, size_t ws_size,
                              hipStream_t stream)
{
    const float* f_atoms = (const float*)d_in[0];
    const float* f_bonds = (const float*)d_in[1];
    const int* a2b    = (const int*)d_in[2];
    const int* b2a    = (const int*)d_in[3];
    const int* b2revb = (const int*)d_in[4];
    const int* gidx   = (const int*)d_in[5];
    const float* W_i    = (const float*)d_in[6];
    const float* W_h    = (const float*)d_in[7];
    const float* W_o    = (const float*)d_in[8];
    const float* b_o    = (const float*)d_in[9];
    const float* W_node = (const float*)d_in[10];
    const float* b_node = (const float*)d_in[11];
    const float* W_edge = (const float*)d_in[12];
    const float* b_edge = (const float*)d_in[13];
    const float* W_g1   = (const float*)d_in[14];
    const float* b_g1   = (const float*)d_in[15];
    const float* W_g2   = (const float*)d_in[16];
    const float* b_g2   = (const float*)d_in[17];

    char* ws = (char*)d_ws;
    u16* inp  = (u16*)(ws + 0);            // 128 MB: inp (pre-relu h1)
    u16* P    = (u16*)(ws + 128000000);    // 128 MB: P buffer; later ah
    u16* rh   = (u16*)(ws + 256000000);    // 128 MB: rh2/rh3 (post-relu msg)
    u16* aP   = (u16*)(ws + 384000000);    // 64 MB: aP / amsg3
    u16* wt_i = (u16*)(ws + 448000000);    // 320x160
    u16* wt_h = (u16*)(ws + 448200000);    // 320x320
    u16* wt_o = (u16*)(ws + 448500000);    // 320x448
    u16* wt_n = (u16*)(ws + 448800000);    // 192x320
    u16* wt_e = (u16*)(ws + 449000000);    // 64x320
    float* gemb = (float*)(ws + 449300000); // 2000x320 f32
    float* gh   = (float*)(ws + 452000000); // 2000x320 f32

    float* out_node  = (float*)d_out;
    float* out_edge  = out_node + (size_t)N_ATOMS * ATOM_FDIM;
    float* out_graph = out_node + 14700000;

    dim3 blk(256);

    // pack weights (bf16, transposed, zero-padded)
    k_pack_wt<<<(320 * 160 + 255) / 256, blk, 0, stream>>>(W_i, wt_i, BOND_FDIM, HIDDEN, 160, 320);
    k_pack_wt<<<(320 * 320 + 255) / 256, blk, 0, stream>>>(W_h, wt_h, HIDDEN, HIDDEN, 320, 320);
    k_pack_wo<<<(320 * CATP + 255) / 256, blk, 0, stream>>>(W_o, wt_o);
    k_pack_wt<<<(192 * 320 + 255) / 256, blk, 0, stream>>>(W_node, wt_n, HIDDEN, ATOM_FDIM, 320, 192);
    k_pack_wt<<<(64 * 320 + 255) / 256, blk, 0, stream>>>(W_edge, wt_e, HIDDEN, 14, 320, 64);

    const int mbB = (N_BONDS + 127) / 128;  // 1563
    const int mbA = (N_ATOMS + 127) / 128;  // 782
    const int gA32 = (N_ATOMS + 31) / 32;
    const int gE128 = (N_EDGES + 127) / 128;
    const int gAg = (N_ATOMS * 40 + 255) / 256;
    const int gCb = (N_BONDS * 40 + 255) / 256;

    // inp = f_bonds @ W_i   (f32 staged in-kernel; pre-relu stored)
    k_gemmL<2, 1, 5, 0><<<dim3(5, mbB), blk, 0, stream>>>(
        nullptr, f_bonds, BOND_FDIM, N_BONDS, wt_i, 160, 0, nullptr, inp);

    // ---- depth 1: P1 = relu(inp) @ W_h ; aP1 ; rh2 ----
    k_gemmL<0, 1, 10, 1><<<dim3(5, mbB), blk, 0, stream>>>(
        inp, nullptr, HP, N_BONDS, wt_h, 320, 0, nullptr, P);
    k_aggregate<<<gAg, blk, 0, stream>>>(P, a2b, aP);
    k_combine<<<gCb, blk, 0, stream>>>(inp, P, aP, b2a, rh);

    // ---- depth 2: P2 = rh2 @ W_h ; aP2 ; rh3 ----
    k_gemmL<0, 1, 10, 0><<<dim3(5, mbB), blk, 0, stream>>>(
        rh, nullptr, HP, N_BONDS, wt_h, 320, 0, nullptr, P);
    k_aggregate<<<gAg, blk, 0, stream>>>(P, a2b, aP);
    k_combine<<<gCb, blk, 0, stream>>>(inp, P, aP, b2a, rh);

    // ---- final: amsg3 = sum rh3[a2b] ; ah = relu([amsg3|f_atoms]@W_o + b_o) ----
    k_aggregate<<<gAg, blk, 0, stream>>>(rh, a2b, aP);
    u16* ah = P; // P dead after combine2
    k_gemmL<3, 3, 14, 0><<<dim3(5, mbA), blk, 0, stream>>>(
        aP, f_atoms, CATP, N_ATOMS, wt_o, CATP, HIDDEN, b_o, ah);

    // node head (linear A, direct; cols 0..191 computed, 0..132 stored)
    k_gemm<0, 0, 10, 3, 0><<<gA32, blk, 0, stream>>>(
        nullptr, ah, nullptr, nullptr, nullptr, HP, N_ATOMS,
        wt_n, 320, ATOM_FDIM, out_node, ATOM_FDIM, b_node, nullptr, nullptr);

    // edge head (fused h_avg gather; waves tile M, 1 col-frag)
    k_gemm<4, 0, 10, 1, 1><<<gE128, blk, 0, stream>>>(
        nullptr, ah, nullptr, b2a, b2revb, 0, N_EDGES,
        wt_e, 320, 14, out_edge, 14, b_edge, nullptr, nullptr);

    // graph head
    k_segsum<<<N_MOLS, 320, 0, stream>>>(ah, gidx, gemb);
    k_g1<<<N_MOLS, 320, 0, stream>>>(gemb, W_g1, b_g1, gh);
    k_g2<<<N_MOLS, 64, 0, stream>>>(gh, W_g2, b_g2, out_graph);
}

// Round 10
// 1084.457 us; speedup vs baseline: 1.3331x; 1.3331x over previous
//
#include <hip/hip_runtime.h>

typedef unsigned short u16;
typedef unsigned int u32;

#define N_ATOMS 100000
#define N_BONDS 200000
#define N_EDGES 100000
#define HIDDEN 300
#define HP 320
#define ATOM_FDIM 133
#define BOND_FDIM 147
#define CATP 448
#define N_MOLS 2000

typedef __bf16 bf16x8 __attribute__((ext_vector_type(8)));
typedef float f32x4 __attribute__((ext_vector_type(4)));

__device__ __forceinline__ u16 f2bf(float f) {
    union { float f; u32 u; } x; x.f = f;
    u32 u = x.u;
    u32 r = u + 0x7fffu + ((u >> 16) & 1u);
    return (u16)(r >> 16);
}
__device__ __forceinline__ float bf2f(u16 h) {
    union { u32 u; float f; } x; x.u = ((u32)h) << 16;
    return x.f;
}

union U8 { uint4 v; u16 h[8]; };
union U4 { uint2 v; u16 h[4]; };

// ============ LDS-staged fused GEMM (R6 structure + latency fixes) ============
// Block: 32 rows x 320 cols, 256 threads = 4 waves (wave w = cols w*80).
// Stage A once (8 threads/row, ONE index chain/thread), one barrier, then a
// barrier-free k-loop: ds_read A + ring-of-3 (2-deep) global B prefetch + MFMA.
// Swapped-operand mfma(B,A): lane holds 4 consecutive output cols.
// M must be a multiple of 32 (all our Ms are).
//  ASRC 0: linear bf16 rows, stride HP (head GEMM reading ah)
//  ASRC 1: f32 rows (f_bonds, width 147), zero-pad
//  ASRC 2: delta = amsg[i1[r]] - relu(h[r^1])   (b2revb[b]==b^1 by construction)
//  ASRC 3: cat [amsg row (304 cols, 300+ zero) | f32 f_atoms (133) | 0]
// EP 1: O1=bf16(acc)
// EP 2: O1=bf16(acc + inp_in)   (inp preloaded before k-loop)
// EP 3: O1=bf16(relu(acc + (col<Nout?bias:0)))
// EP 4: col<133 -> F1[row*133+col]=acc+bias[col] (node preds, f32)
//       133<=col<147 -> F2[row*16+col-133]=acc+bias2[col-133] (E buffer)
template<int ASRC, int EP, int KSTEPS>
__global__ __launch_bounds__(256, 4) void k_gemm_lds(
    const u16* __restrict__ srcA, const u16* __restrict__ srcB,
    const float* __restrict__ fsrc, const int* __restrict__ i1,
    const u16* __restrict__ Bt, int ldb, int Nout,
    const float* __restrict__ bias, const float* __restrict__ bias2,
    u16* __restrict__ O1, float* __restrict__ F1, float* __restrict__ F2,
    const u16* __restrict__ inp_in)
{
    constexpr int CHPR = KSTEPS * 4;                 // 16B chunks per row
    constexpr int MASK = (CHPR % 8 == 0) ? 7 : 3;    // XOR swizzle domain
    constexpr int CPT = (CHPR + 7) / 8;              // chunks per stage thread
    __shared__ __align__(16) u16 As[32 * CHPR * 8];

    const int tid = threadIdx.x;
    const int row0 = blockIdx.x * 32;

    // ---- stage A tile: 8 threads per row, one idx chain per thread ----
    {
        const int rr = tid >> 3;          // row in tile 0..31
        const int cc = tid & 7;           // chunk lane
        const int row = row0 + rr;
        const u16* px = nullptr; const u16* py = nullptr; const float* pf = nullptr;
        if constexpr (ASRC == 0) px = srcA + (size_t)row * HP;
        if constexpr (ASRC == 1) pf = fsrc + (size_t)row * BOND_FDIM;
        if constexpr (ASRC == 2) {
            px = srcA + (size_t)i1[row] * HP;          // gathered amsg
            py = srcB + (size_t)(row ^ 1) * HP;        // linear: b2revb[b]=b^1
        }
        if constexpr (ASRC == 3) { px = srcA + (size_t)row * HP; pf = fsrc + (size_t)row * ATOM_FDIM; }
#pragma unroll
        for (int j = 0; j < CPT; j++) {
            const int c = cc + 8 * j;
            if (CPT * 8 != CHPR && c >= CHPR) continue;
            U8 u;
            if constexpr (ASRC == 0) {
                u.v = *(const uint4*)(px + c * 8);
            } else if constexpr (ASRC == 1) {
#pragma unroll
                for (int e = 0; e < 8; e++) {
                    int col = c * 8 + e;
                    u.h[e] = (col < BOND_FDIM) ? f2bf(pf[col]) : (u16)0;
                }
            } else if constexpr (ASRC == 2) {
                U8 x, y;
                x.v = *(const uint4*)(px + c * 8);
                y.v = *(const uint4*)(py + c * 8);
#pragma unroll
                for (int e = 0; e < 8; e++)
                    u.h[e] = f2bf(bf2f(x.h[e]) - fmaxf(bf2f(y.h[e]), 0.f));
            } else {
                if (c < 38) {
                    u.v = *(const uint4*)(px + c * 8);
                } else {
#pragma unroll
                    for (int e = 0; e < 8; e++) {
                        int col = c * 8 + e - 304;
                        u.h[e] = (col >= 0 && col < ATOM_FDIM) ? f2bf(pf[col]) : (u16)0;
                    }
                }
            }
            *(uint4*)&As[(size_t)(rr * CHPR + (c ^ (rr & MASK))) * 8] = u.v;
        }
    }

    // ---- consumer setup ----
    const int lane = tid & 63;
    const int wv = tid >> 6;
    const int ncol0 = wv * 80;
    const int lrow = lane & 15;
    const int g = lane >> 4;
    const int lkb = g * 8;
    const int xr = lrow & MASK;

    const u16* pb[5];
#pragma unroll
    for (int n = 0; n < 5; n++)
        pb[n] = Bt + (size_t)(ncol0 + n * 16 + lrow) * ldb + lkb;

    // EP2: pre-issue epilogue inp loads (hidden under the k-loop)
    U4 ii[10];
    if constexpr (EP == 2) {
#pragma unroll
        for (int m = 0; m < 2; m++)
#pragma unroll
            for (int n = 0; n < 5; n++)
                ii[m * 5 + n].v = *(const uint2*)&inp_in[
                    (size_t)(row0 + m * 16 + lrow) * HP + ncol0 + n * 16 + g * 4];
    }

    __syncthreads();

    // ---- barrier-free MFMA loop, B 2-deep prefetch (ring of 3) ----
    f32x4 acc[2][5] = {};
    bf16x8 bb[3][5];
#pragma unroll
    for (int n = 0; n < 5; n++) bb[0][n] = *(const bf16x8*)(pb[n]);
    if constexpr (KSTEPS > 1) {
#pragma unroll
        for (int n = 0; n < 5; n++) bb[1][n] = *(const bf16x8*)(pb[n] + 32);
    }

#pragma unroll
    for (int ks = 0; ks < KSTEPS; ks++) {
        if (ks + 2 < KSTEPS) {
#pragma unroll
            for (int n = 0; n < 5; n++)
                bb[(ks + 2) % 3][n] = *(const bf16x8*)(pb[n] + (ks + 2) * 32);
        }
        const int sw = (ks * 4 + g) ^ xr;
        bf16x8 a0 = *(const bf16x8*)&As[(size_t)(lrow * CHPR + sw) * 8];
        bf16x8 a1 = *(const bf16x8*)&As[(size_t)((lrow + 16) * CHPR + sw) * 8];
#pragma unroll
        for (int n = 0; n < 5; n++) {
            acc[0][n] = __builtin_amdgcn_mfma_f32_16x16x32_bf16(bb[ks % 3][n], a0, acc[0][n], 0, 0, 0);
            acc[1][n] = __builtin_amdgcn_mfma_f32_16x16x32_bf16(bb[ks % 3][n], a1, acc[1][n], 0, 0, 0);
        }
    }

    // ---- epilogue: lane owns rows row0+m*16+lrow, cols ncol0+n*16+g*4+q ----
#pragma unroll
    for (int m = 0; m < 2; m++) {
        const int row = row0 + m * 16 + lrow;
#pragma unroll
        for (int n = 0; n < 5; n++) {
            const int colb = ncol0 + n * 16 + g * 4;
            if constexpr (EP == 4) {
                if (colb >= 148) continue;
#pragma unroll
                for (int q = 0; q < 4; q++) {
                    const int col = colb + q;
                    const float v = acc[m][n][q];
                    if (col < 133) F1[(size_t)row * 133 + col] = v + bias[col];
                    else if (col < 147) F2[(size_t)row * 16 + (col - 133)] = v + bias2[col - 133];
                }
            } else {
                U4 o;
                if constexpr (EP == 1) {
#pragma unroll
                    for (int q = 0; q < 4; q++) o.h[q] = f2bf(acc[m][n][q]);
                } else if constexpr (EP == 2) {
#pragma unroll
                    for (int q = 0; q < 4; q++) o.h[q] = f2bf(acc[m][n][q] + bf2f(ii[m * 5 + n].h[q]));
                } else {
#pragma unroll
                    for (int q = 0; q < 4; q++) {
                        float x = acc[m][n][q] + ((colb + q) < Nout ? bias[colb + q] : 0.f);
                        o.h[q] = f2bf(fmaxf(x, 0.f));
                    }
                }
                *(uint2*)&O1[(size_t)row * HP + colb] = o.v;
            }
        }
    }
}

// ---------------- weight pack: Bt[n][k] = W[k][n], bf16, zero-padded ----------------
__global__ void k_pack_wt(const float* __restrict__ W, u16* __restrict__ Bt,
                          int K, int N, int Kp, int Np)
{
    int idx = blockIdx.x * 256 + threadIdx.x;
    if (idx >= Np * Kp) return;
    int n = idx / Kp, k = idx - n * Kp;
    Bt[idx] = (n < N && k < K) ? f2bf(W[(size_t)k * N + n]) : (u16)0;
}

// W_o pack with the [amsg(300) | pad4 | f_atoms(133) | pad] column reorder
__global__ void k_pack_wo(const float* __restrict__ W, u16* __restrict__ Bt)
{
    int idx = blockIdx.x * 256 + threadIdx.x;
    if (idx >= 320 * CATP) return;
    int n = idx / CATP, k = idx - n * CATP;
    float v = 0.f;
    if (n < HIDDEN) {
        if (k < HIDDEN) v = W[(size_t)(ATOM_FDIM + k) * HIDDEN + n];
        else if (k >= 304 && k < 304 + ATOM_FDIM) v = W[(size_t)(k - 304) * HIDDEN + n];
    }
    Bt[idx] = f2bf(v);
}

// merged head pack: Bt_ne[n][k]: n<133 from W_node, 133<=n<147 from W_edge
__global__ void k_pack_wne(const float* __restrict__ Wn, const float* __restrict__ We,
                           u16* __restrict__ Bt)
{
    int idx = blockIdx.x * 256 + threadIdx.x;
    if (idx >= 320 * 320) return;
    int n = idx / 320, k = idx - n * 320;
    float v = 0.f;
    if (k < HIDDEN) {
        if (n < ATOM_FDIM) v = Wn[(size_t)k * ATOM_FDIM + n];
        else if (n < ATOM_FDIM + 14) v = We[(size_t)k * 14 + (n - ATOM_FDIM)];
    }
    Bt[idx] = f2bf(v);
}

// ---------------- a_msg[a] = sum_j relu(h[a2b[a][j]]) ----------------
__global__ __launch_bounds__(256) void k_aggregate(const u16* __restrict__ h,
    const int* __restrict__ a2b, u16* __restrict__ amsg)
{
    int idx = blockIdx.x * 256 + threadIdx.x;
    if (idx >= N_ATOMS * 40) return;
    int a = idx / 40, c = (idx - a * 40) * 8;
    float s[8] = {};
#pragma unroll
    for (int j = 0; j < 6; j++) {
        int b = a2b[a * 6 + j];
        U8 u; u.v = *(const uint4*)&h[(size_t)b * HP + c];
#pragma unroll
        for (int i = 0; i < 8; i++) s[i] += fmaxf(bf2f(u.h[i]), 0.f);
    }
    U8 o;
#pragma unroll
    for (int i = 0; i < 8; i++) o.h[i] = f2bf(s[i]);
    *(uint4*)&amsg[(size_t)a * HP + c] = o.v;
}

// -------- edge head finish: out[e] = 0.5*(E[b2a[2e]] + E[b2a[2e+1]]) --------
__global__ __launch_bounds__(256) void k_edge(const float* __restrict__ E,
    const int* __restrict__ b2a, float* __restrict__ out)
{
    int idx = blockIdx.x * 256 + threadIdx.x;
    if (idx >= N_EDGES * 7) return;
    int e = idx / 7, p = idx - e * 7;
    int a1 = b2a[2 * e], a2 = b2a[2 * e + 1];
    float2 x = *(const float2*)&E[(size_t)a1 * 16 + 2 * p];
    float2 y = *(const float2*)&E[(size_t)a2 * 16 + 2 * p];
    float2 o; o.x = 0.5f * (x.x + y.x); o.y = 0.5f * (x.y + y.y);
    *(float2*)&out[(size_t)e * 14 + 2 * p] = o;
}

// ---------------- per-molecule segment sum (graph_idx sorted) ----------------
__device__ __forceinline__ int lower_bound_i(const int* a, int n, int v) {
    int lo = 0, hi = n;
    while (lo < hi) { int mid = (lo + hi) >> 1; if (a[mid] < v) lo = mid + 1; else hi = mid; }
    return lo;
}
__global__ __launch_bounds__(320) void k_segsum(const u16* __restrict__ ah,
    const int* __restrict__ gidx, float* __restrict__ gemb)
{
    int g = blockIdx.x;
    int c = threadIdx.x;
    int s = lower_bound_i(gidx, N_ATOMS, g);
    int e = lower_bound_i(gidx, N_ATOMS, g + 1);
    float sum = 0.f;
    for (int a = s; a < e; a++) sum += bf2f(ah[(size_t)a * HP + c]);
    gemb[(size_t)g * HP + c] = sum;
}

// ---------------- graph head (fp32) ----------------
__global__ __launch_bounds__(320) void k_g1(const float* __restrict__ gemb,
    const float* __restrict__ W, const float* __restrict__ b, float* __restrict__ gh)
{
    int g = blockIdx.x, j = threadIdx.x;
    float acc = 0.f;
    if (j < HIDDEN) {
        acc = b[j];
        for (int k = 0; k < HIDDEN; k++)
            acc = fmaf(gemb[(size_t)g * HP + k], W[(size_t)k * HIDDEN + j], acc);
        acc = fmaxf(acc, 0.f);
    }
    gh[(size_t)g * HP + j] = (j < HIDDEN) ? acc : 0.f;
}
__global__ __launch_bounds__(64) void k_g2(const float* __restrict__ gh,
    const float* __restrict__ W, const float* __restrict__ b, float* __restrict__ out)
{
    int g = blockIdx.x, l = threadIdx.x;
    float acc = 0.f;
    for (int j = l; j < HIDDEN; j += 64) acc += gh[(size_t)g * HP + j] * W[j];
#pragma unroll
    for (int off = 32; off; off >>= 1) acc += __shfl_down(acc, off, 64);
    if (l == 0) out[g] = acc + b[0];
}

extern "C" void kernel_launch(void* const* d_in, const int* in_sizes, int n_in,
                              void* d_out, int out_size, void* d_ws, size_t ws_size,
                              hipStream_t stream)
{
    const float* f_atoms = (const float*)d_in[0];
    const float* f_bonds = (const float*)d_in[1];
    const int* a2b    = (const int*)d_in[2];
    const int* b2a    = (const int*)d_in[3];
    const int* gidx   = (const int*)d_in[5];
    const float* W_i    = (const float*)d_in[6];
    const float* W_h    = (const float*)d_in[7];
    const float* W_o    = (const float*)d_in[8];
    const float* b_o    = (const float*)d_in[9];
    const float* W_node = (const float*)d_in[10];
    const float* b_node = (const float*)d_in[11];
    const float* W_edge = (const float*)d_in[12];
    const float* b_edge = (const float*)d_in[13];
    const float* W_g1   = (const float*)d_in[14];
    const float* b_g1   = (const float*)d_in[15];
    const float* W_g2   = (const float*)d_in[16];
    const float* b_g2   = (const float*)d_in[17];

    char* ws = (char*)d_ws;
    u16* inp   = (u16*)(ws + 0);            // 128 MB (h1 pre-relu)
    u16* hA    = (u16*)(ws + 128000000);    // 128 MB: h2 -> ah
    u16* hB    = (u16*)(ws + 256000000);    // 128 MB: h3 -> Ebuf
    u16* amsg  = (u16*)(ws + 384000000);    // 64 MB
    u16* wt_i  = (u16*)(ws + 448000000);    // 320x160
    u16* wt_h  = (u16*)(ws + 448200000);    // 320x320
    u16* wt_o  = (u16*)(ws + 448500000);    // 320x448
    u16* wt_ne = (u16*)(ws + 448800000);    // 320x320
    float* gemb = (float*)(ws + 449300000); // 2000x320 f32
    float* gh   = (float*)(ws + 452000000); // 2000x320 f32

    float* out_node  = (float*)d_out;
    float* out_edge  = out_node + (size_t)N_ATOMS * ATOM_FDIM;
    float* out_graph = out_node + 14700000;

    dim3 blk(256);

    // pack weights (bf16, transposed, zero-padded)
    k_pack_wt<<<(320 * 160 + 255) / 256, blk, 0, stream>>>(W_i, wt_i, BOND_FDIM, HIDDEN, 160, 320);
    k_pack_wt<<<(320 * 320 + 255) / 256, blk, 0, stream>>>(W_h, wt_h, HIDDEN, HIDDEN, 320, 320);
    k_pack_wo<<<(320 * CATP + 255) / 256, blk, 0, stream>>>(W_o, wt_o);
    k_pack_wne<<<(320 * 320 + 255) / 256, blk, 0, stream>>>(W_node, W_edge, wt_ne);

    const int gB32 = N_BONDS / 32;    // 6250
    const int gA32 = N_ATOMS / 32;    // 3125
    const int gAg = (N_ATOMS * 40 + 255) / 256;

    // inp = f_bonds @ W_i  (f32 staged in-kernel; pre-relu stored)
    k_gemm_lds<1, 1, 5><<<gB32, blk, 0, stream>>>(
        nullptr, nullptr, f_bonds, nullptr,
        wt_i, 160, 0, nullptr, nullptr, inp, nullptr, nullptr, nullptr);

    // depth loop: h_{d+1} = inp + (amsg[b2a] - relu(h_d[b^1])) @ W_h
    const u16* hcur = inp;
    u16* houts[2] = { hA, hB };
    for (int d = 0; d < 2; ++d) {
        k_aggregate<<<gAg, blk, 0, stream>>>(hcur, a2b, amsg);
        k_gemm_lds<2, 2, 10><<<gB32, blk, 0, stream>>>(
            amsg, hcur, nullptr, b2a,
            wt_h, 320, 0, nullptr, nullptr, houts[d], nullptr, nullptr, inp);
        hcur = houts[d];
    }

    // final aggregate + fused-concat W_o -> atom_hiddens (relu'd, bf16) in hA
    k_aggregate<<<gAg, blk, 0, stream>>>(hcur, a2b, amsg);
    u16* ah = hA;   // h2 fully consumed
    k_gemm_lds<3, 3, 14><<<gA32, blk, 0, stream>>>(
        amsg, nullptr, f_atoms, nullptr,
        wt_o, CATP, HIDDEN, b_o, nullptr, ah, nullptr, nullptr, nullptr);

    // merged node+edge head: cols 0..132 -> node preds, 133..146 -> E buffer
    float* Ebuf = (float*)hB;   // h3 dead after aggregate
    k_gemm_lds<0, 4, 10><<<gA32, blk, 0, stream>>>(
        ah, nullptr, nullptr, nullptr,
        wt_ne, 320, 0, b_node, b_edge, nullptr, out_node, Ebuf, nullptr);

    // edge head finish: average endpoint E rows
    k_edge<<<(N_EDGES * 7 + 255) / 256, blk, 0, stream>>>(Ebuf, b2a, out_edge);

    // graph head
    k_segsum<<<N_MOLS, 320, 0, stream>>>(ah, gidx, gemb);
    k_g1<<<N_MOLS, 320, 0, stream>>>(gemb, W_g1, b_g1, gh);
    k_g2<<<N_MOLS, 64, 0, stream>>>(gh, W_g2, b_g2, out_graph);
}